// Round 2
// baseline (403.703 us; speedup 1.0000x reference)
//
#include <hip/hip_runtime.h>

typedef _Float16 f16;
typedef f16 f16x2 __attribute__((ext_vector_type(2)));
typedef f16 f16x4 __attribute__((ext_vector_type(4)));
typedef f16 f16x8 __attribute__((ext_vector_type(8)));
typedef float f32x4 __attribute__((ext_vector_type(4)));

#define MFMA16(a, b, c) __builtin_amdgcn_mfma_f32_16x16x32_f16((a), (b), (c), 0, 0, 0)

__device__ __forceinline__ f16x8 cat8(f16x4 a, f16x4 b) {
    return __builtin_shufflevector(a, b, 0, 1, 2, 3, 4, 5, 6, 7);
}
__device__ __forceinline__ f16x4 lo4(f16x8 v) { return __builtin_shufflevector(v, v, 0, 1, 2, 3); }
__device__ __forceinline__ f16x4 hi4(f16x8 v) { return __builtin_shufflevector(v, v, 4, 5, 6, 7); }

// ---------------- LDS layout for the fused attention kernel (bytes) ----------------
// VT : f16 [128][264]  V''^T[co][t]   (V'' = X@Wo^T + bo)        67584
// YL : f16 [256][72]   psi rows=token, cols m                    36864
// SC : per-wave 4608 B scratch: T-exchange [32][72] f16,
//      then P staging [16][36] f16 (rows 0-15 only, disjoint from
//      T's mt=1 half at rows 16-31), then store-transpose [16][136]
// SST: f32 [256] block BN-stat partials
#define LDS_VT  0
#define LDS_YL  67584
#define LDS_SC  (67584 + 36864)
#define LDS_SST (LDS_SC + 8 * 4608)
#define LDS_ATT (LDS_SST + 1024)   // 142336 <= 163840

// =====================================================================================
// repack: x fp32 [B,C,H,W] -> Xall f16 [b][n2=(i2,j2)][n1=(i1,j1)][c]
// =====================================================================================
__global__ __launch_bounds__(512) void repack_kernel(const float* __restrict__ x,
                                                     f16* __restrict__ Xall) {
    __shared__ f16 XT[128 * 264];     // [c][w], padded
    const int tid = threadIdx.x, g = blockIdx.x;
    const int b = g >> 8, i1 = (g >> 4) & 15, i2 = g & 15;
    const int h = i1 * 16 + i2;
    {
        const int c = tid >> 2, wq = (tid & 3) * 64;
        const float* src = x + (((size_t)b * 128 + c) * 256 + h) * 256 + wq;
        f16* dst = XT + c * 264 + wq;
#pragma unroll
        for (int i = 0; i < 16; ++i) {
            f32x4 v = *(const f32x4*)(src + i * 4);
            f16x4 o = {(f16)v[0], (f16)v[1], (f16)v[2], (f16)v[3]};
            *(f16x4*)(dst + i * 4) = o;
        }
    }
    __syncthreads();
    {
        const int w = tid >> 1, ch = (tid & 1) * 64;   // w = j1*16 + j2
        const int j1 = w >> 4, j2 = w & 15;
        f16* dst = Xall + (((size_t)b * 256 + i2 * 16 + j2) * 256 + i1 * 16 + j1) * 128 + ch;
#pragma unroll
        for (int i = 0; i < 8; ++i) {
            f16x8 v;
#pragma unroll
            for (int j = 0; j < 8; ++j) v[j] = XT[(ch + i * 8 + j) * 264 + w];
            *(f16x8*)(dst + i * 8) = v;
        }
    }
}

// =====================================================================================
// weight conversion fp32 -> f16
// =====================================================================================
__global__ void wconv_kernel(const float* __restrict__ w1x, const float* __restrict__ w1y,
                             const float* __restrict__ w1o, const float* __restrict__ w2x,
                             const float* __restrict__ w2y, const float* __restrict__ w2o,
                             f16* __restrict__ Wbf) {
    int i = blockIdx.x * 256 + threadIdx.x;
    float v;
    if (i < 8192)       v = w1x[i];
    else if (i < 16384) v = w1y[i - 8192];
    else if (i < 32768) v = w1o[i - 16384];
    else if (i < 40960) v = w2x[i - 32768];
    else if (i < 49152) v = w2y[i - 40960];
    else                v = w2o[i - 49152];
    Wbf[i] = (f16)v;
}

// =====================================================================================
// fused per-block attention, V''-factored:
//   out = softmax(theta psi) @ (X Wo^T + bo)   (exact: softmax rows sum to 1)
// X consumed only as MFMA A-operand -> loaded directly from global (no X in LDS).
// 2 barriers total. Writes pre-BN out f16; accumulates BN stats.
// =====================================================================================
template <int PASS>
__global__ __launch_bounds__(512, 2) void att_kernel(
    const f16* __restrict__ Xin, const f16* __restrict__ Wq, const f16* __restrict__ Wk,
    const f16* __restrict__ Wo, const float* __restrict__ bq, const float* __restrict__ bk,
    const float* __restrict__ bo, const float* __restrict__ bnab, f16* __restrict__ Uout,
    float* __restrict__ gstats, int t_stride, int s_stride) {
    __shared__ __align__(16) char smem[LDS_ATT];
    f16* VT = (f16*)(smem + LDS_VT);
    f16* YL = (f16*)(smem + LDS_YL);
    float* SST = (float*)(smem + LDS_SST);

    const int tid = threadIdx.x;
    const int w = tid >> 6, l = tid & 63, lq = l >> 4, lr = l & 15;
    const int g = blockIdx.x, R0 = w * 32;
    f16* sc = (f16*)(smem + LDS_SC) + w * 2304;   // per-wave scratch, f16 units

    if (tid < 256) SST[tid] = 0.f;

    // ---- X A-fragments from global (shared by V''-GEMM and GEMM1) ----
    const f16* src = Xin + (size_t)g * 32768;
    f16x8 afr[2][4];
#pragma unroll
    for (int mt = 0; mt < 2; ++mt)
#pragma unroll
        for (int ks = 0; ks < 4; ++ks)
            afr[mt][ks] = *(const f16x8*)(src + (R0 + mt * 16 + lr) * 128 + ks * 32 + lq * 8);
    if constexpr (PASS == 2) {   // BN1 + ReLU on the fly
#pragma unroll
        for (int ks = 0; ks < 4; ++ks) {
            const int c0 = ks * 32 + lq * 8;
            f32x4 a0 = *(const f32x4*)(bnab + c0), a1 = *(const f32x4*)(bnab + c0 + 4);
            f32x4 s0 = *(const f32x4*)(bnab + 128 + c0), s1 = *(const f32x4*)(bnab + 132 + c0);
#pragma unroll
            for (int mt = 0; mt < 2; ++mt) {
                f16x8 v = afr[mt][ks];
#pragma unroll
                for (int j = 0; j < 4; ++j) {
                    v[j]     = (f16)fmaxf(a0[j] * (float)v[j]     + s0[j], 0.f);
                    v[j + 4] = (f16)fmaxf(a1[j] * (float)v[j + 4] + s1[j], 0.f);
                }
                afr[mt][ks] = v;
            }
        }
    }

    // ---- V'' = X @ Wo^T + bo  ->  VT[co][t] ----
    {
        f32x4 accV[2][8] = {};
#pragma unroll
        for (int ks = 0; ks < 4; ++ks)
#pragma unroll
            for (int ct = 0; ct < 8; ++ct) {
                f16x8 bw = *(const f16x8*)(Wo + (ct * 16 + lr) * 128 + ks * 32 + lq * 8);
#pragma unroll
                for (int mt = 0; mt < 2; ++mt) accV[mt][ct] = MFMA16(afr[mt][ks], bw, accV[mt][ct]);
            }
#pragma unroll
        for (int ct = 0; ct < 8; ++ct) {
            float bov = bo[ct * 16 + lr];
#pragma unroll
            for (int mt = 0; mt < 2; ++mt)
#pragma unroll
                for (int r = 0; r < 4; ++r)
                    VT[(ct * 16 + lr) * 264 + R0 + mt * 16 + lq * 4 + r] =
                        (f16)(accV[mt][ct][r] + bov);
        }
    }

    // ---- GEMM1: T = X@Wq^T + bq (per-wave, -> sc); psi rows = X@Wk^T + bk (-> YL) ----
    {
        f32x4 accT[2][4] = {}, accY[2][4] = {};
#pragma unroll
        for (int ks = 0; ks < 4; ++ks)
#pragma unroll
            for (int nt = 0; nt < 4; ++nt) {
                f16x8 bq8 = *(const f16x8*)(Wq + (nt * 16 + lr) * 128 + ks * 32 + lq * 8);
                f16x8 bk8 = *(const f16x8*)(Wk + (nt * 16 + lr) * 128 + ks * 32 + lq * 8);
#pragma unroll
                for (int mt = 0; mt < 2; ++mt) {
                    accT[mt][nt] = MFMA16(afr[mt][ks], bq8, accT[mt][nt]);
                    accY[mt][nt] = MFMA16(afr[mt][ks], bk8, accY[mt][nt]);
                }
            }
#pragma unroll
        for (int nt = 0; nt < 4; ++nt) {
            float bqv = bq[nt * 16 + lr], bkv = bk[nt * 16 + lr];
#pragma unroll
            for (int mt = 0; mt < 2; ++mt)
#pragma unroll
                for (int r = 0; r < 4; ++r) {
                    int nl = mt * 16 + lq * 4 + r;
                    sc[nl * 72 + nt * 16 + lr] = (f16)(accT[mt][nt][r] + bqv);
                    YL[(R0 + nl) * 72 + nt * 16 + lr] = (f16)(accY[mt][nt][r] + bkv);
                }
        }
    }
    __syncthreads();   // b1: YL + VT complete

    // ---- per-16-row half: S = T.psi^T, softmax, out-half += P @ V'' ----
    f32x4 g5[2][8] = {};
#pragma unroll
    for (int mt = 0; mt < 2; ++mt) {
        f16x8 a2[2];
#pragma unroll
        for (int ks = 0; ks < 2; ++ks)
            a2[ks] = *(const f16x8*)(sc + (mt * 16 + lr) * 72 + ks * 32 + lq * 8);
        f32x4 s[16] = {};
#pragma unroll
        for (int kt = 0; kt < 16; ++kt)
#pragma unroll
            for (int ks = 0; ks < 2; ++ks) {
                f16x8 b2 = *(const f16x8*)(YL + (kt * 16 + lr) * 72 + ks * 32 + lq * 8);
                s[kt] = MFMA16(a2[ks], b2, s[kt]);
            }
        float rs[4];
#pragma unroll
        for (int r = 0; r < 4; ++r) {
            float m = -1e30f;
#pragma unroll
            for (int kt = 0; kt < 16; ++kt) m = fmaxf(m, s[kt][r]);
#pragma unroll
            for (int off = 1; off < 16; off <<= 1) m = fmaxf(m, __shfl_xor(m, off));
            float sum = 0.f;
#pragma unroll
            for (int kt = 0; kt < 16; ++kt) {
                float p = __expf(s[kt][r] - m);
                s[kt][r] = p;
                sum += p;
            }
#pragma unroll
            for (int off = 1; off < 16; off <<= 1) sum += __shfl_xor(sum, off);
            rs[r] = 1.f / sum;
        }
        // PV: stage P in per-wave PS (sc rows 0-15, disjoint from T's mt=1 half)
        f16* PS = sc;
#pragma unroll
        for (int kc = 0; kc < 8; ++kc) {
#pragma unroll
            for (int d = 0; d < 2; ++d) {
                int kt = kc * 2 + d;
#pragma unroll
                for (int r = 0; r < 4; ++r)
                    PS[(lq * 4 + r) * 36 + d * 16 + lr] = (f16)(s[kt][r] * rs[r]);
            }
            f16x8 ap = cat8(*(const f16x4*)(PS + lr * 36 + lq * 8),
                            *(const f16x4*)(PS + lr * 36 + lq * 8 + 4));
#pragma unroll
            for (int ct = 0; ct < 8; ++ct) {
                f16x8 bv = *(const f16x8*)(VT + (ct * 16 + lr) * 264 + kc * 32 + lq * 8);
                g5[mt][ct] = MFMA16(ap, bv, g5[mt][ct]);
            }
        }
    }

    // ---- epilogue: BN-stat partials + vectorized store via per-wave transpose ----
    const size_t ub = (size_t)(g >> 8) * 8388608 + (size_t)(g & 255) * (size_t)s_stride;
#pragma unroll
    for (int mt = 0; mt < 2; ++mt) {
#pragma unroll
        for (int ct = 0; ct < 8; ++ct) {
            float ss = 0.f, sq = 0.f;
#pragma unroll
            for (int r = 0; r < 4; ++r) {
                float v = g5[mt][ct][r];
                ss += v;
                sq += v * v;
            }
            ss += __shfl_xor(ss, 16); ss += __shfl_xor(ss, 32);
            sq += __shfl_xor(sq, 16); sq += __shfl_xor(sq, 32);
            if (lq == 0) {
                atomicAdd(&SST[ct * 16 + lr], ss);
                atomicAdd(&SST[128 + ct * 16 + lr], sq);
            }
        }
#pragma unroll
        for (int ct = 0; ct < 8; ++ct)
#pragma unroll
            for (int r = 0; r < 4; ++r)
                sc[(lq * 4 + r) * 136 + ct * 16 + lr] = (f16)g5[mt][ct][r];
#pragma unroll
        for (int i = 0; i < 4; ++i) {
            int rowl = i * 4 + lq;
            f16x8 v8 = *(const f16x8*)(sc + rowl * 136 + lr * 8);
            *(f16x8*)(Uout + ub + (size_t)(R0 + mt * 16 + rowl) * (size_t)t_stride + lr * 8) = v8;
        }
    }
    __syncthreads();   // b2
    if (tid < 256) atomicAdd(&gstats[tid], SST[tid]);
}

// =====================================================================================
// BN stats finalize: (sum, sumsq) -> (a, b) with y = a*x + b
// =====================================================================================
__global__ void bnfix_kernel(const float* __restrict__ gstats, const float* __restrict__ gamma,
                             const float* __restrict__ beta, float* __restrict__ ab) {
    int c = threadIdx.x;
    if (c < 128) {
        const float inv = 1.f / 262144.f;
        float mean = gstats[c] * inv;
        float var = gstats[128 + c] * inv - mean * mean;
        float rstd = rsqrtf(var + 1e-5f);
        float a = gamma[c] * rstd;
        ab[c] = a;
        ab[128 + c] = beta[c] - mean * a;
    }
}

// =====================================================================================
// final: U2 f16 [b][n1][n2][c] -> BN2+ReLU -> out fp32 [B,C,H,W]
// =====================================================================================
__global__ __launch_bounds__(256) void final_kernel(const f16* __restrict__ U2,
                                                    const float* __restrict__ ab,
                                                    float* __restrict__ out) {
    __shared__ f16 L[256 * 132];      // [n2][c] padded
    const int tid = threadIdx.x, g = blockIdx.x;
    const int b = g >> 8, i1 = (g >> 4) & 15, j1 = g & 15;
    const f16* src = U2 + (size_t)g * 32768;
#pragma unroll
    for (int e = 0; e < 16; ++e) {
        int u = e * 2048 + tid * 8;
        int row = u >> 7, c0 = u & 127;
        f16x8 v = *(const f16x8*)(src + u);
        f16* dst = L + row * 132 + c0;
        *(f16x4*)dst = lo4(v);
        *(f16x4*)(dst + 4) = hi4(v);
    }
    __syncthreads();
    const int j2 = tid & 15, bu = tid >> 4;
#pragma unroll 4
    for (int k = 0; k < 128; ++k) {
        int unit = bu + k * 16;        // 0..2047 -> (c, i2)
        int c = unit & 127, i2 = unit >> 7;
        float a = ab[c], bb = ab[128 + c];
        float v = fmaxf(a * (float)L[(i2 * 16 + j2) * 132 + c] + bb, 0.f);
        out[(((size_t)b * 128 + c) * 256 + i1 * 16 + i2) * 256 + j1 * 16 + j2] = v;
    }
}

// =====================================================================================
extern "C" void kernel_launch(void* const* d_in, const int* in_sizes, int n_in, void* d_out,
                              int out_size, void* d_ws, size_t ws_size, hipStream_t stream) {
    (void)in_sizes; (void)n_in; (void)out_size; (void)ws_size;
    const float* x = (const float*)d_in[0];
    const float* w1x = (const float*)d_in[1];
    const float* b1x = (const float*)d_in[2];
    const float* w1y = (const float*)d_in[3];
    const float* b1y = (const float*)d_in[4];
    const float* w1o = (const float*)d_in[5];
    const float* b1o = (const float*)d_in[6];
    const float* g1 = (const float*)d_in[7];
    const float* be1 = (const float*)d_in[8];
    const float* w2x = (const float*)d_in[9];
    const float* b2x = (const float*)d_in[10];
    const float* w2y = (const float*)d_in[11];
    const float* b2y = (const float*)d_in[12];
    const float* w2o = (const float*)d_in[13];
    const float* b2o = (const float*)d_in[14];
    const float* g2 = (const float*)d_in[15];
    const float* be2 = (const float*)d_in[16];

    // d_out doubles as scratch: [0,64MiB) Xall f16, [64MiB,128MiB) U1 f16 (both dead
    // before final_kernel rewrites d_out as fp32).
    f16* Xall = (f16*)d_out;
    f16* U1 = (f16*)((char*)d_out + 67108864);
    f16* U2 = (f16*)d_ws;
    f16* Wbf = (f16*)((char*)d_ws + 67108864);
    float* gstats = (float*)((char*)d_ws + 67108864 + 131072);  // [2][256]
    float* bnab = gstats + 512;                                 // [2][256]

    hipMemsetAsync(gstats, 0, 2048, stream);
    wconv_kernel<<<256, 256, 0, stream>>>(w1x, w1y, w1o, w2x, w2y, w2o, Wbf);
    repack_kernel<<<1024, 512, 0, stream>>>(x, Xall);

    att_kernel<1><<<1024, 512, 0, stream>>>(Xall, Wbf, Wbf + 8192, Wbf + 16384, b1x, b1y, b1o,
                                            (const float*)nullptr, U1, gstats, 32768, 128);
    bnfix_kernel<<<1, 128, 0, stream>>>(gstats, g1, be1, bnab);
    att_kernel<2><<<1024, 512, 0, stream>>>(U1, Wbf + 32768, Wbf + 40960, Wbf + 49152, b2x, b2y,
                                            b2o, bnab, U2, gstats + 256, 128, 32768);
    bnfix_kernel<<<1, 128, 0, stream>>>(gstats + 256, g2, be2, bnab + 256);
    final_kernel<<<1024, 256, 0, stream>>>(U2, bnab + 256, (float*)d_out);
}

// Round 3
// 307.768 us; speedup vs baseline: 1.3117x; 1.3117x over previous
//
#include <hip/hip_runtime.h>

typedef _Float16 f16;
typedef f16 f16x2 __attribute__((ext_vector_type(2)));
typedef f16 f16x4 __attribute__((ext_vector_type(4)));
typedef f16 f16x8 __attribute__((ext_vector_type(8)));
typedef float f32x4 __attribute__((ext_vector_type(4)));

#define MFMA16(a, b, c) __builtin_amdgcn_mfma_f32_16x16x32_f16((a), (b), (c), 0, 0, 0)

__device__ __forceinline__ f16x4 lo4(f16x8 v) { return __builtin_shufflevector(v, v, 0, 1, 2, 3); }
__device__ __forceinline__ f16x4 hi4(f16x8 v) { return __builtin_shufflevector(v, v, 4, 5, 6, 7); }

// ---------------- LDS layout (bytes) ----------------
// [0,65536):      phase1 W fused [256 rows][256B], swizzled; phase2 VT [128 c][512B t]
// [65536,98304):  YL psi^T [256 k][128B m], swizzled
// [98304,139264): per-wave 5120B scratch: T [32][128B] (phase1->S^T B), then
//                 P 2-slot stream [16][80B]x2, then epi transpose [16][256B]
// [139264,140288): SST f32[256] BN partials
#define OFF_YL  65536
#define OFF_SC  98304
#define OFF_SST 139264
#define LDS_ATT 140288

// =====================================================================================
// repack: x fp32 [B,C,H,W] -> Xall f16 [b][n2=(i2,j2)][n1=(i1,j1)][c]
// =====================================================================================
__global__ __launch_bounds__(512) void repack_kernel(const float* __restrict__ x,
                                                     f16* __restrict__ Xall) {
    __shared__ f16 XT[128 * 264];     // [c][w], padded
    const int tid = threadIdx.x, g = blockIdx.x;
    const int b = g >> 8, i1 = (g >> 4) & 15, i2 = g & 15;
    const int h = i1 * 16 + i2;
    {
        const int c = tid >> 2, wq = (tid & 3) * 64;
        const float* src = x + (((size_t)b * 128 + c) * 256 + h) * 256 + wq;
        f16* dst = XT + c * 264 + wq;
#pragma unroll
        for (int i = 0; i < 16; ++i) {
            f32x4 v = *(const f32x4*)(src + i * 4);
            f16x4 o = {(f16)v[0], (f16)v[1], (f16)v[2], (f16)v[3]};
            *(f16x4*)(dst + i * 4) = o;
        }
    }
    __syncthreads();
    {
        const int w = tid >> 1, ch = (tid & 1) * 64;   // w = j1*16 + j2
        const int j1 = w >> 4, j2 = w & 15;
        f16* dst = Xall + (((size_t)b * 256 + i2 * 16 + j2) * 256 + i1 * 16 + j1) * 128 + ch;
#pragma unroll
        for (int i = 0; i < 8; ++i) {
            f16x8 v;
#pragma unroll
            for (int j = 0; j < 8; ++j) v[j] = XT[(ch + i * 8 + j) * 264 + w];
            *(f16x8*)(dst + i * 8) = v;
        }
    }
}

// =====================================================================================
// weight conversion fp32 -> f16, fused per-pass layout [Wo(128) ; Wq(64) ; Wk(64)][128]
// =====================================================================================
__global__ void wconv_kernel(const float* __restrict__ w1x, const float* __restrict__ w1y,
                             const float* __restrict__ w1o, const float* __restrict__ w2x,
                             const float* __restrict__ w2y, const float* __restrict__ w2o,
                             f16* __restrict__ Wf) {
    int i = blockIdx.x * 256 + threadIdx.x;      // 65536 total
    int p = i >> 15, r = (i >> 7) & 255, c = i & 127;
    const float* s;
    if (p == 0) s = (r < 128) ? w1o + r * 128 : (r < 192) ? w1x + (r - 128) * 128
                                                          : w1y + (r - 192) * 128;
    else        s = (r < 128) ? w2o + r * 128 : (r < 192) ? w2x + (r - 128) * 128
                                                          : w2y + (r - 192) * 128;
    Wf[i] = (f16)s[c];
}

// =====================================================================================
// fused per-block attention: out = softmax(theta psi) @ (X Wo^T + bo)
// Phase1: W in LDS (swizzled) -> V''/theta/psi GEMMs (X A-frags from global).
// Phase2: S^T (softmax on lane axis), P streamed via per-wave LDS slots, PV from VT.
// =====================================================================================
template <int PASS>
__global__ __launch_bounds__(512, 2) void att_kernel(
    const f16* __restrict__ Xin, const f16* __restrict__ Wf, const float* __restrict__ bq,
    const float* __restrict__ bk, const float* __restrict__ bo, const float* __restrict__ bnab,
    f16* __restrict__ Uout, float* __restrict__ gstats, int t_stride, int s_stride) {
    __shared__ __align__(16) char smem[LDS_ATT];
    float* SST = (float*)(smem + OFF_SST);
    const int tid = threadIdx.x;
    const int w = tid >> 6, l = tid & 63, lq = l >> 4, lr = l & 15;
    const int g = blockIdx.x, R0 = w * 32;
    char* scb = smem + OFF_SC + w * 5120;
    const unsigned swz = (unsigned)((lr & 7) << 4);

    if (tid < 256) SST[tid] = 0.f;

    // ---- W preload: 64KB reg-staged, swizzle rows of 256B ----
#pragma unroll
    for (int j = 0; j < 8; ++j) {
        int byte = (j * 512 + tid) * 16;
        f16x8 v = *(const f16x8*)((const char*)Wf + byte);
        *(f16x8*)(smem + (byte ^ (((byte >> 8) & 7) << 4))) = v;
    }

    // ---- X A-fragments (global, 64B segments, L2/L3-hot) ----
    const f16* src = Xin + (size_t)g * 32768;
    f16x8 afr[2][4];
#pragma unroll
    for (int mt = 0; mt < 2; ++mt)
#pragma unroll
        for (int ks = 0; ks < 4; ++ks)
            afr[mt][ks] = *(const f16x8*)(src + (R0 + mt * 16 + lr) * 128 + ks * 32 + lq * 8);
    if constexpr (PASS == 2) {   // BN1 + ReLU on the fly
#pragma unroll
        for (int ks = 0; ks < 4; ++ks) {
            const int c0 = ks * 32 + lq * 8;
            f32x4 a0 = *(const f32x4*)(bnab + c0), a1 = *(const f32x4*)(bnab + c0 + 4);
            f32x4 s0 = *(const f32x4*)(bnab + 128 + c0), s1 = *(const f32x4*)(bnab + 132 + c0);
#pragma unroll
            for (int mt = 0; mt < 2; ++mt) {
                f16x8 v = afr[mt][ks];
#pragma unroll
                for (int j = 0; j < 4; ++j) {
                    v[j]     = (f16)fmaxf(a0[j] * (float)v[j]     + s0[j], 0.f);
                    v[j + 4] = (f16)fmaxf(a1[j] * (float)v[j + 4] + s1[j], 0.f);
                }
                afr[mt][ks] = v;
            }
        }
    }
    __syncthreads();   // #0: W resident

    unsigned wb[4];
#pragma unroll
    for (int ks = 0; ks < 4; ++ks) wb[ks] = (unsigned)((lr * 256 + ks * 64 + lq * 16) ^ swz);

    // ---- theta/psi GEMMs (B from LDS W rows 128..255) ----
    {
        f32x4 aT[2][4] = {}, aP[2][4] = {};
#pragma unroll
        for (int ks = 0; ks < 4; ++ks) {
            f16x8 Bq[4], Bk[4];
#pragma unroll
            for (int nt = 0; nt < 4; ++nt) {
                Bq[nt] = *(const f16x8*)(smem + wb[ks] + (8 + nt) * 4096);
                Bk[nt] = *(const f16x8*)(smem + wb[ks] + (12 + nt) * 4096);
            }
#pragma unroll
            for (int nt = 0; nt < 4; ++nt)
#pragma unroll
                for (int mt = 0; mt < 2; ++mt) {
                    aT[mt][nt] = MFMA16(afr[mt][ks], Bq[nt], aT[mt][nt]);
                    aP[mt][nt] = MFMA16(afr[mt][ks], Bk[nt], aP[mt][nt]);
                }
        }
        float bqv[4], bkv[4];
#pragma unroll
        for (int nt = 0; nt < 4; ++nt) { bqv[nt] = bq[nt * 16 + lr]; bkv[nt] = bk[nt * 16 + lr]; }
        // scatter: T[t][m] per-wave (S^T B-operand), psi^T[k][m] shared
#pragma unroll
        for (int mt = 0; mt < 2; ++mt)
#pragma unroll
            for (int nt = 0; nt < 4; ++nt)
#pragma unroll
                for (int r = 0; r < 4; ++r) {
                    int tl = mt * 16 + lq * 4 + r;
                    int m2 = (nt * 16 + lr) * 2;
                    *(f16*)(scb + ((unsigned)(tl * 128 + m2) ^ (unsigned)((tl & 7) << 4))) =
                        (f16)(aT[mt][nt][r] + bqv[nt]);
                    int k = R0 + tl;
                    *(f16*)(smem + OFF_YL + ((unsigned)(k * 128 + m2) ^ (unsigned)((k & 7) << 4))) =
                        (f16)(aP[mt][nt][r] + bkv[nt]);
                }
    }

    // ---- V'' GEMM (B from LDS W rows 0..127), park in regs ----
    f32x4 aV[2][8] = {};
#pragma unroll
    for (int ks = 0; ks < 4; ++ks) {
        f16x8 Bo[8];
#pragma unroll
        for (int ct = 0; ct < 8; ++ct) Bo[ct] = *(const f16x8*)(smem + wb[ks] + ct * 4096);
#pragma unroll
        for (int ct = 0; ct < 8; ++ct)
#pragma unroll
            for (int mt = 0; mt < 2; ++mt) aV[mt][ct] = MFMA16(afr[mt][ks], Bo[ct], aV[mt][ct]);
    }
    __syncthreads();   // #1: all W reads done -> region reusable as VT

    // ---- scatter V''+bo -> VT[c][t] (rows 512B, swizzled) ----
    {
        float bov[8];
#pragma unroll
        for (int ct = 0; ct < 8; ++ct) bov[ct] = bo[ct * 16 + lr];
#pragma unroll
        for (int ct = 0; ct < 8; ++ct)
#pragma unroll
            for (int mt = 0; mt < 2; ++mt)
#pragma unroll
                for (int r = 0; r < 4; ++r) {
                    int t = R0 + mt * 16 + lq * 4 + r;
                    *(f16*)(smem + ((unsigned)(lr * 512 + ct * 8192 + t * 2) ^ swz)) =
                        (f16)(aV[mt][ct][r] + bov[ct]);
                }
    }
    __syncthreads();   // #2: VT complete

    // ---- hoist T B-frags (own rows; T region reused by P/epi below) ----
    f16x8 tb[2][2];
#pragma unroll
    for (int tt = 0; tt < 2; ++tt)
#pragma unroll
        for (int ks = 0; ks < 2; ++ks)
            tb[tt][ks] = *(const f16x8*)(scb +
                ((unsigned)(lr * 128 + tt * 2048 + ks * 64 + lq * 16) ^ swz));

    unsigned yb[2], vb[2];
#pragma unroll
    for (int ks = 0; ks < 2; ++ks) yb[ks] = (unsigned)((lr * 128 + ks * 64 + lq * 16) ^ swz);
#pragma unroll
    for (int p = 0; p < 2; ++p) vb[p] = (unsigned)((lr * 512 + p * 64 + lq * 16) ^ swz);

    const size_t ub = (size_t)(g >> 8) * 8388608 + (size_t)(g & 255) * (size_t)s_stride;

#pragma unroll
    for (int tt = 0; tt < 2; ++tt) {
        // ---- S^T: column t = R0+tt*16+lr on lane axis, all 256 k in regs ----
        f32x4 s[16] = {};
#pragma unroll
        for (int kt = 0; kt < 16; ++kt)
#pragma unroll
            for (int ks = 0; ks < 2; ++ks) {
                f16x8 ay = *(const f16x8*)(smem + OFF_YL + yb[ks] + kt * 2048);
                s[kt] = MFMA16(ay, tb[tt][ks], s[kt]);
            }
        // ---- softmax over k: per-lane 64 values + cross-lq reduce ----
        float mx = -1e30f;
#pragma unroll
        for (int kt = 0; kt < 16; ++kt)
            mx = fmaxf(mx, fmaxf(fmaxf(s[kt][0], s[kt][1]), fmaxf(s[kt][2], s[kt][3])));
        mx = fmaxf(mx, __shfl_xor(mx, 16));
        mx = fmaxf(mx, __shfl_xor(mx, 32));
        float sum = 0.f;
#pragma unroll
        for (int kt = 0; kt < 16; ++kt)
#pragma unroll
            for (int r = 0; r < 4; ++r) {
                float p = __expf(s[kt][r] - mx);
                s[kt][r] = p;
                sum += p;
            }
        sum += __shfl_xor(sum, 16);
        sum += __shfl_xor(sum, 32);
        const float rs = 1.f / sum;

        // ---- PV: stream P through 2-slot per-wave buffer; B from VT ----
        f32x4 o[8] = {};
#pragma unroll
        for (int kc = 0; kc < 8; ++kc) {
            char* slot = scb + (kc & 1) * 1280;
#pragma unroll
            for (int h = 0; h < 2; ++h) {
                f32x4 sv = s[kc * 2 + h];
                f16x4 pv = {(f16)(sv[0] * rs), (f16)(sv[1] * rs),
                            (f16)(sv[2] * rs), (f16)(sv[3] * rs)};
                *(f16x4*)(slot + lr * 80 + h * 32 + lq * 8) = pv;
            }
            f16x8 ap = *(const f16x8*)(slot + lr * 80 + lq * 16);
#pragma unroll
            for (int ct = 0; ct < 8; ++ct) {
                f16x8 bv = *(const f16x8*)(smem + vb[kc & 1] + ct * 8192 + (kc >> 1) * 128);
                o[ct] = MFMA16(ap, bv, o[ct]);
            }
        }

        // ---- epilogue tt: BN stats + transpose-store (per-wave epi region) ----
#pragma unroll
        for (int ct = 0; ct < 8; ++ct) {
            float ss = (o[ct][0] + o[ct][1]) + (o[ct][2] + o[ct][3]);
            float sq = o[ct][0] * o[ct][0] + o[ct][1] * o[ct][1] +
                       o[ct][2] * o[ct][2] + o[ct][3] * o[ct][3];
            ss += __shfl_xor(ss, 16); ss += __shfl_xor(ss, 32);
            sq += __shfl_xor(sq, 16); sq += __shfl_xor(sq, 32);
            if (lq == 0) {
                atomicAdd(&SST[ct * 16 + lr], ss);
                atomicAdd(&SST[128 + ct * 16 + lr], sq);
            }
        }
#pragma unroll
        for (int ct = 0; ct < 8; ++ct)
#pragma unroll
            for (int r = 0; r < 4; ++r) {
                int tl = lq * 4 + r;
                *(f16*)(scb + ((unsigned)(tl * 256 + (ct * 16 + lr) * 2) ^
                               (unsigned)((tl & 7) << 4))) = (f16)o[ct][r];
            }
#pragma unroll
        for (int i = 0; i < 4; ++i) {
            int tl = i * 4 + lq;
            f16x8 v8 = *(const f16x8*)(scb + ((unsigned)(tl * 256 + lr * 16) ^
                                              (unsigned)((tl & 7) << 4)));
            *(f16x8*)(Uout + ub + (size_t)(R0 + tt * 16 + tl) * (size_t)t_stride + lr * 8) = v8;
        }
    }
    __syncthreads();   // #3
    if (tid < 256) atomicAdd(&gstats[tid], SST[tid]);
}

// =====================================================================================
// BN stats finalize: (sum, sumsq) -> (a, b) with y = a*x + b
// =====================================================================================
__global__ void bnfix_kernel(const float* __restrict__ gstats, const float* __restrict__ gamma,
                             const float* __restrict__ beta, float* __restrict__ ab) {
    int c = threadIdx.x;
    if (c < 128) {
        const float inv = 1.f / 262144.f;
        float mean = gstats[c] * inv;
        float var = gstats[128 + c] * inv - mean * mean;
        float rstd = rsqrtf(var + 1e-5f);
        float a = gamma[c] * rstd;
        ab[c] = a;
        ab[128 + c] = beta[c] - mean * a;
    }
}

// =====================================================================================
// final: U2 f16 [b][n1][n2][c] -> BN2+ReLU -> out fp32 [B,C,H,W]
// =====================================================================================
__global__ __launch_bounds__(256) void final_kernel(const f16* __restrict__ U2,
                                                    const float* __restrict__ ab,
                                                    float* __restrict__ out) {
    __shared__ f16 L[256 * 132];      // [n2][c] padded
    const int tid = threadIdx.x, g = blockIdx.x;
    const int b = g >> 8, i1 = (g >> 4) & 15, j1 = g & 15;
    const f16* src = U2 + (size_t)g * 32768;
#pragma unroll
    for (int e = 0; e < 16; ++e) {
        int u = e * 2048 + tid * 8;
        int row = u >> 7, c0 = u & 127;
        f16x8 v = *(const f16x8*)(src + u);
        f16* dst = L + row * 132 + c0;
        *(f16x4*)dst = lo4(v);
        *(f16x4*)(dst + 4) = hi4(v);
    }
    __syncthreads();
    const int j2 = tid & 15, bu = tid >> 4;
#pragma unroll 4
    for (int k = 0; k < 128; ++k) {
        int unit = bu + k * 16;        // 0..2047 -> (c, i2)
        int c = unit & 127, i2 = unit >> 7;
        float a = ab[c], bb = ab[128 + c];
        float v = fmaxf(a * (float)L[(i2 * 16 + j2) * 132 + c] + bb, 0.f);
        out[(((size_t)b * 128 + c) * 256 + i1 * 16 + i2) * 256 + j1 * 16 + j2] = v;
    }
}

// =====================================================================================
extern "C" void kernel_launch(void* const* d_in, const int* in_sizes, int n_in, void* d_out,
                              int out_size, void* d_ws, size_t ws_size, hipStream_t stream) {
    (void)in_sizes; (void)n_in; (void)out_size; (void)ws_size;
    const float* x = (const float*)d_in[0];
    const float* w1x = (const float*)d_in[1];
    const float* b1x = (const float*)d_in[2];
    const float* w1y = (const float*)d_in[3];
    const float* b1y = (const float*)d_in[4];
    const float* w1o = (const float*)d_in[5];
    const float* b1o = (const float*)d_in[6];
    const float* g1 = (const float*)d_in[7];
    const float* be1 = (const float*)d_in[8];
    const float* w2x = (const float*)d_in[9];
    const float* b2x = (const float*)d_in[10];
    const float* w2y = (const float*)d_in[11];
    const float* b2y = (const float*)d_in[12];
    const float* w2o = (const float*)d_in[13];
    const float* b2o = (const float*)d_in[14];
    const float* g2 = (const float*)d_in[15];
    const float* be2 = (const float*)d_in[16];

    // d_out doubles as scratch: [0,64MiB) Xall f16, [64MiB,128MiB) U1 f16 (both dead
    // before final_kernel rewrites d_out as fp32).
    f16* Xall = (f16*)d_out;
    f16* U1 = (f16*)((char*)d_out + 67108864);
    f16* U2 = (f16*)d_ws;
    f16* Wbf = (f16*)((char*)d_ws + 67108864);                  // fused [2][256][128] f16
    float* gstats = (float*)((char*)d_ws + 67108864 + 131072);  // [2][256]
    float* bnab = gstats + 512;                                 // [2][256]

    hipMemsetAsync(gstats, 0, 2048, stream);
    wconv_kernel<<<256, 256, 0, stream>>>(w1x, w1y, w1o, w2x, w2y, w2o, Wbf);
    repack_kernel<<<1024, 512, 0, stream>>>(x, Xall);

    att_kernel<1><<<1024, 512, 0, stream>>>(Xall, Wbf, b1x, b1y, b1o, (const float*)nullptr, U1,
                                            gstats, 32768, 128);
    bnfix_kernel<<<1, 128, 0, stream>>>(gstats, g1, be1, bnab);
    att_kernel<2><<<1024, 512, 0, stream>>>(U1, Wbf + 32768, b2x, b2y, b2o, bnab, U2,
                                            gstats + 256, 128, 32768);
    bnfix_kernel<<<1, 128, 0, stream>>>(gstats + 256, g2, be2, bnab + 256);
    final_kernel<<<1024, 256, 0, stream>>>(U2, bnab + 256, (float*)d_out);
}

// Round 5
// 299.527 us; speedup vs baseline: 1.3478x; 1.0275x over previous
//
#include <hip/hip_runtime.h>

typedef _Float16 f16;
typedef f16 f16x2 __attribute__((ext_vector_type(2)));
typedef f16 f16x4 __attribute__((ext_vector_type(4)));
typedef f16 f16x8 __attribute__((ext_vector_type(8)));
typedef float f32x4 __attribute__((ext_vector_type(4)));

#define MFMA16(a, b, c) __builtin_amdgcn_mfma_f32_16x16x32_f16((a), (b), (c), 0, 0, 0)

__device__ __forceinline__ f16x4 lo4(f16x8 v) { return __builtin_shufflevector(v, v, 0, 1, 2, 3); }
__device__ __forceinline__ f16x4 hi4(f16x8 v) { return __builtin_shufflevector(v, v, 4, 5, 6, 7); }

__device__ __forceinline__ f16x4 pk4(float a, float b, float c, float d) {
    f16x2 lo = __builtin_bit_cast(f16x2, __builtin_amdgcn_cvt_pkrtz(a, b));
    f16x2 hi = __builtin_bit_cast(f16x2, __builtin_amdgcn_cvt_pkrtz(c, d));
    return f16x4{lo[0], lo[1], hi[0], hi[1]};
}

// ---------------- LDS layout (bytes) ----------------
// [0,65536):      phase1 W fused [256 rows][256B], swizzled; phase2 VT [128 c][512B t]
// [65536,98304):  YL psi^T [256 k][128B m], swizzled
// [98304,139264): per-wave 5120B scratch: T [32][128B], then P slots [2][16][80B],
//                 then epi transpose [16][256B]
// [139264,140288): SST f32[256] BN partials
#define OFF_YL  65536
#define OFF_SC  98304
#define OFF_SST 139264
#define LDS_ATT 140288

// =====================================================================================
// repack: x fp32 [B,C,H,W] -> Xall f16 [b][n2=(i2,j2)][n1=(i1,j1)][c]
// =====================================================================================
__global__ __launch_bounds__(512) void repack_kernel(const float* __restrict__ x,
                                                     f16* __restrict__ Xall) {
    __shared__ f16 XT[128 * 264];     // [c][w], padded
    const int tid = threadIdx.x, g = blockIdx.x;
    const int b = g >> 8, i1 = (g >> 4) & 15, i2 = g & 15;
    const int h = i1 * 16 + i2;
    {
        const int c = tid >> 2, wq = (tid & 3) * 64;
        const float* src = x + (((size_t)b * 128 + c) * 256 + h) * 256 + wq;
        f16* dst = XT + c * 264 + wq;
#pragma unroll
        for (int i = 0; i < 16; ++i) {
            f32x4 v = *(const f32x4*)(src + i * 4);
            f16x4 o = {(f16)v[0], (f16)v[1], (f16)v[2], (f16)v[3]};
            *(f16x4*)(dst + i * 4) = o;
        }
    }
    __syncthreads();
    {
        const int w = tid >> 1, ch = (tid & 1) * 64;   // w = j1*16 + j2
        const int j1 = w >> 4, j2 = w & 15;
        f16* dst = Xall + (((size_t)b * 256 + i2 * 16 + j2) * 256 + i1 * 16 + j1) * 128 + ch;
#pragma unroll
        for (int i = 0; i < 8; ++i) {
            f16x8 v;
#pragma unroll
            for (int j = 0; j < 8; ++j) v[j] = XT[(ch + i * 8 + j) * 264 + w];
            *(f16x8*)(dst + i * 8) = v;
        }
    }
}

// =====================================================================================
// weight conversion fp32 -> f16, fused per-pass layout [Wo(128) ; Wq(64) ; Wk(64)][128]
// =====================================================================================
__global__ void wconv_kernel(const float* __restrict__ w1x, const float* __restrict__ w1y,
                             const float* __restrict__ w1o, const float* __restrict__ w2x,
                             const float* __restrict__ w2y, const float* __restrict__ w2o,
                             f16* __restrict__ Wf) {
    int i = blockIdx.x * 256 + threadIdx.x;      // 65536 total
    int p = i >> 15, r = (i >> 7) & 255, c = i & 127;
    const float* s;
    if (p == 0) s = (r < 128) ? w1o + r * 128 : (r < 192) ? w1x + (r - 128) * 128
                                                          : w1y + (r - 192) * 128;
    else        s = (r < 128) ? w2o + r * 128 : (r < 192) ? w2x + (r - 128) * 128
                                                          : w2y + (r - 192) * 128;
    Wf[i] = (f16)s[c];
}

// =====================================================================================
// fused per-block attention: out = softmax(theta psi) @ (X Wo^T + bo)
// Phase1: W in LDS (swizzled) -> V''/theta/psi GEMMs (X A-frags from global).
// Phase2: S^T merged over both 16-row halves (single YL pass, single VT pass),
//         P packed to f16 in-register, streamed via per-wave LDS slots.
// =====================================================================================
template <int PASS>
__global__ __launch_bounds__(512, 2) void att_kernel(
    const f16* __restrict__ Xin, const f16* __restrict__ Wf, const float* __restrict__ bq,
    const float* __restrict__ bk, const float* __restrict__ bo, const float* __restrict__ bnab,
    f16* __restrict__ Uout, float* __restrict__ gstats, int t_stride, int s_stride) {
    __shared__ __align__(16) char smem[LDS_ATT];
    float* SST = (float*)(smem + OFF_SST);
    const int tid = threadIdx.x;
    const int w = tid >> 6, l = tid & 63, lq = l >> 4, lr = l & 15;
    const int g = blockIdx.x, R0 = w * 32;
    char* scb = smem + OFF_SC + w * 5120;
    const unsigned swz = (unsigned)((lr & 7) << 4);

    if (tid < 256) SST[tid] = 0.f;

    // ---- W preload: 64KB reg-staged, swizzle rows of 256B ----
#pragma unroll
    for (int j = 0; j < 8; ++j) {
        int byte = (j * 512 + tid) * 16;
        f16x8 v = *(const f16x8*)((const char*)Wf + byte);
        *(f16x8*)(smem + (byte ^ (((byte >> 8) & 7) << 4))) = v;
    }

    // ---- X A-fragments (global, 64B segments, L2/L3-hot) ----
    const f16* src = Xin + (size_t)g * 32768;
    f16x8 afr[2][4];
#pragma unroll
    for (int mt = 0; mt < 2; ++mt)
#pragma unroll
        for (int ks = 0; ks < 4; ++ks)
            afr[mt][ks] = *(const f16x8*)(src + (R0 + mt * 16 + lr) * 128 + ks * 32 + lq * 8);
    if constexpr (PASS == 2) {   // BN1 + ReLU on the fly
#pragma unroll
        for (int ks = 0; ks < 4; ++ks) {
            const int c0 = ks * 32 + lq * 8;
            f32x4 a0 = *(const f32x4*)(bnab + c0), a1 = *(const f32x4*)(bnab + c0 + 4);
            f32x4 s0 = *(const f32x4*)(bnab + 128 + c0), s1 = *(const f32x4*)(bnab + 132 + c0);
#pragma unroll
            for (int mt = 0; mt < 2; ++mt) {
                f16x8 v = afr[mt][ks];
#pragma unroll
                for (int j = 0; j < 4; ++j) {
                    v[j]     = (f16)fmaxf(a0[j] * (float)v[j]     + s0[j], 0.f);
                    v[j + 4] = (f16)fmaxf(a1[j] * (float)v[j + 4] + s1[j], 0.f);
                }
                afr[mt][ks] = v;
            }
        }
    }
    __syncthreads();   // #0: W resident

    unsigned wb[4];
#pragma unroll
    for (int ks = 0; ks < 4; ++ks) wb[ks] = (unsigned)((lr * 256 + ks * 64 + lq * 16) ^ swz);

    // ---- theta/psi GEMMs (B from LDS W rows 128..255) ----
    {
        f32x4 aT[2][4] = {}, aP[2][4] = {};
#pragma unroll
        for (int ks = 0; ks < 4; ++ks) {
            f16x8 Bq[4], Bk[4];
#pragma unroll
            for (int nt = 0; nt < 4; ++nt) {
                Bq[nt] = *(const f16x8*)(smem + wb[ks] + (8 + nt) * 4096);
                Bk[nt] = *(const f16x8*)(smem + wb[ks] + (12 + nt) * 4096);
            }
#pragma unroll
            for (int nt = 0; nt < 4; ++nt)
#pragma unroll
                for (int mt = 0; mt < 2; ++mt) {
                    aT[mt][nt] = MFMA16(afr[mt][ks], Bq[nt], aT[mt][nt]);
                    aP[mt][nt] = MFMA16(afr[mt][ks], Bk[nt], aP[mt][nt]);
                }
        }
        float bqv[4], bkv[4];
#pragma unroll
        for (int nt = 0; nt < 4; ++nt) { bqv[nt] = bq[nt * 16 + lr]; bkv[nt] = bk[nt * 16 + lr]; }
        // scatter: T[t][m] per-wave (S^T B-operand), psi^T[k][m] shared
#pragma unroll
        for (int mt = 0; mt < 2; ++mt)
#pragma unroll
            for (int nt = 0; nt < 4; ++nt)
#pragma unroll
                for (int r = 0; r < 4; ++r) {
                    int tl = mt * 16 + lq * 4 + r;
                    int m2 = (nt * 16 + lr) * 2;
                    *(f16*)(scb + ((unsigned)(tl * 128 + m2) ^ (unsigned)((tl & 7) << 4))) =
                        (f16)(aT[mt][nt][r] + bqv[nt]);
                    int k = R0 + tl;
                    *(f16*)(smem + OFF_YL + ((unsigned)(k * 128 + m2) ^ (unsigned)((k & 7) << 4))) =
                        (f16)(aP[mt][nt][r] + bkv[nt]);
                }
    }

    // ---- V'' GEMM (B from LDS W rows 0..127), park in regs ----
    f32x4 aV[2][8] = {};
#pragma unroll
    for (int ks = 0; ks < 4; ++ks) {
        f16x8 Bo[8];
#pragma unroll
        for (int ct = 0; ct < 8; ++ct) Bo[ct] = *(const f16x8*)(smem + wb[ks] + ct * 4096);
#pragma unroll
        for (int ct = 0; ct < 8; ++ct)
#pragma unroll
            for (int mt = 0; mt < 2; ++mt) aV[mt][ct] = MFMA16(afr[mt][ks], Bo[ct], aV[mt][ct]);
    }
    __syncthreads();   // #1: all W reads done -> region reusable as VT

    // ---- scatter V''+bo -> VT[c][t] (rows 512B, swizzled), packed b64 ----
    {
        float bov[8];
#pragma unroll
        for (int ct = 0; ct < 8; ++ct) bov[ct] = bo[ct * 16 + lr];
#pragma unroll
        for (int ct = 0; ct < 8; ++ct)
#pragma unroll
            for (int mt = 0; mt < 2; ++mt) {
                int t0 = R0 + mt * 16 + lq * 4;
                f16x4 pv = pk4(aV[mt][ct][0] + bov[ct], aV[mt][ct][1] + bov[ct],
                               aV[mt][ct][2] + bov[ct], aV[mt][ct][3] + bov[ct]);
                *(f16x4*)(smem + ((unsigned)(lr * 512 + ct * 8192 + t0 * 2) ^ swz)) = pv;
            }
    }
    __syncthreads();   // #2: VT complete

    // ---- hoist T B-frags (own rows; T region reused by P/epi below) ----
    f16x8 tb[2][2];
#pragma unroll
    for (int tt = 0; tt < 2; ++tt)
#pragma unroll
        for (int ks = 0; ks < 2; ++ks)
            tb[tt][ks] = *(const f16x8*)(scb +
                ((unsigned)(lr * 128 + tt * 2048 + ks * 64 + lq * 16) ^ swz));

    unsigned yb[2], vb[2];
#pragma unroll
    for (int ks = 0; ks < 2; ++ks) yb[ks] = (unsigned)((lr * 128 + ks * 64 + lq * 16) ^ swz);
#pragma unroll
    for (int p = 0; p < 2; ++p) vb[p] = (unsigned)((lr * 512 + p * 64 + lq * 16) ^ swz);

    // ---- S^T both halves in one YL pass: col t = R0+tt*16+lr on lane axis ----
    f32x4 s[2][16] = {};
    __builtin_amdgcn_s_setprio(1);
#pragma unroll
    for (int kt = 0; kt < 16; ++kt)
#pragma unroll
        for (int ks = 0; ks < 2; ++ks) {
            f16x8 ay = *(const f16x8*)(smem + OFF_YL + yb[ks] + kt * 2048);
            s[0][kt] = MFMA16(ay, tb[0][ks], s[0][kt]);
            s[1][kt] = MFMA16(ay, tb[1][ks], s[1][kt]);
        }
    __builtin_amdgcn_s_setprio(0);

    // ---- softmax over k (per-lane 64 + cross-lq), pack P to f16 in-register ----
    f16x4 p16[2][16];
#pragma unroll
    for (int tt = 0; tt < 2; ++tt) {
        float mx = -1e30f;
#pragma unroll
        for (int kt = 0; kt < 16; ++kt)
            mx = fmaxf(mx, fmaxf(fmaxf(s[tt][kt][0], s[tt][kt][1]),
                                 fmaxf(s[tt][kt][2], s[tt][kt][3])));
        mx = fmaxf(mx, __shfl_xor(mx, 16));
        mx = fmaxf(mx, __shfl_xor(mx, 32));
        float sum = 0.f;
#pragma unroll
        for (int kt = 0; kt < 16; ++kt)
#pragma unroll
            for (int r = 0; r < 4; ++r) {
                float p = __expf(s[tt][kt][r] - mx);
                s[tt][kt][r] = p;
                sum += p;
            }
        sum += __shfl_xor(sum, 16);
        sum += __shfl_xor(sum, 32);
        const float rs = 1.f / sum;
#pragma unroll
        for (int kt = 0; kt < 16; ++kt)
            p16[tt][kt] = pk4(s[tt][kt][0] * rs, s[tt][kt][1] * rs,
                              s[tt][kt][2] * rs, s[tt][kt][3] * rs);
    }

    // ---- PV single VT pass: stage both halves' P, 2 MFMAs per bv read ----
    f32x4 o[2][8] = {};
#pragma unroll
    for (int kc = 0; kc < 8; ++kc) {
#pragma unroll
        for (int tt = 0; tt < 2; ++tt) {
            char* slot = scb + tt * 1280;
#pragma unroll
            for (int h = 0; h < 2; ++h)
                *(f16x4*)(slot + lr * 80 + h * 32 + lq * 8) = p16[tt][kc * 2 + h];
        }
        f16x8 ap0 = *(const f16x8*)(scb + lr * 80 + lq * 16);
        f16x8 ap1 = *(const f16x8*)(scb + 1280 + lr * 80 + lq * 16);
        __builtin_amdgcn_s_setprio(1);
#pragma unroll
        for (int ct = 0; ct < 8; ++ct) {
            f16x8 bv = *(const f16x8*)(smem + vb[kc & 1] + ct * 8192 + (kc >> 1) * 128);
            o[0][ct] = MFMA16(ap0, bv, o[0][ct]);
            o[1][ct] = MFMA16(ap1, bv, o[1][ct]);
        }
        __builtin_amdgcn_s_setprio(0);
    }

    // ---- epilogue: BN stats + transpose-store (per-wave epi region) ----
    const size_t ub = (size_t)(g >> 8) * 8388608 + (size_t)(g & 255) * (size_t)s_stride;
#pragma unroll
    for (int tt = 0; tt < 2; ++tt) {
#pragma unroll
        for (int ct = 0; ct < 8; ++ct) {
            float ss = (o[tt][ct][0] + o[tt][ct][1]) + (o[tt][ct][2] + o[tt][ct][3]);
            float sq = o[tt][ct][0] * o[tt][ct][0] + o[tt][ct][1] * o[tt][ct][1] +
                       o[tt][ct][2] * o[tt][ct][2] + o[tt][ct][3] * o[tt][ct][3];
            ss += __shfl_xor(ss, 16); ss += __shfl_xor(ss, 32);
            sq += __shfl_xor(sq, 16); sq += __shfl_xor(sq, 32);
            if (lq == 0) {
                atomicAdd(&SST[ct * 16 + lr], ss);
                atomicAdd(&SST[128 + ct * 16 + lr], sq);
            }
        }
#pragma unroll
        for (int ct = 0; ct < 8; ++ct)
#pragma unroll
            for (int r = 0; r < 4; ++r) {
                int tl = lq * 4 + r;
                *(f16*)(scb + ((unsigned)(tl * 256 + (ct * 16 + lr) * 2) ^
                               (unsigned)((tl & 7) << 4))) = (f16)o[tt][ct][r];
            }
#pragma unroll
        for (int i = 0; i < 4; ++i) {
            int tl = i * 4 + lq;
            f16x8 v8 = *(const f16x8*)(scb + ((unsigned)(tl * 256 + lr * 16) ^
                                              (unsigned)((tl & 7) << 4)));
            *(f16x8*)(Uout + ub + (size_t)(R0 + tt * 16 + tl) * (size_t)t_stride + lr * 8) = v8;
        }
    }
    __syncthreads();   // #3
    if (tid < 256) atomicAdd(&gstats[tid], SST[tid]);
}

// =====================================================================================
// BN stats finalize: (sum, sumsq) -> (a, b) with y = a*x + b
// =====================================================================================
__global__ void bnfix_kernel(const float* __restrict__ gstats, const float* __restrict__ gamma,
                             const float* __restrict__ beta, float* __restrict__ ab) {
    int c = threadIdx.x;
    if (c < 128) {
        const float inv = 1.f / 262144.f;
        float mean = gstats[c] * inv;
        float var = gstats[128 + c] * inv - mean * mean;
        float rstd = rsqrtf(var + 1e-5f);
        float a = gamma[c] * rstd;
        ab[c] = a;
        ab[128 + c] = beta[c] - mean * a;
    }
}

// =====================================================================================
// final: U2 f16 [b][n1][n2][c] -> BN2+ReLU -> out fp32 [B,C,H,W]
// =====================================================================================
__global__ __launch_bounds__(256) void final_kernel(const f16* __restrict__ U2,
                                                    const float* __restrict__ ab,
                                                    float* __restrict__ out) {
    __shared__ f16 L[256 * 132];      // [n2][c] padded
    const int tid = threadIdx.x, g = blockIdx.x;
    const int b = g >> 8, i1 = (g >> 4) & 15, j1 = g & 15;
    const f16* src = U2 + (size_t)g * 32768;
#pragma unroll
    for (int e = 0; e < 16; ++e) {
        int u = e * 2048 + tid * 8;
        int row = u >> 7, c0 = u & 127;
        f16x8 v = *(const f16x8*)(src + u);
        f16* dst = L + row * 132 + c0;
        *(f16x4*)dst = lo4(v);
        *(f16x4*)(dst + 4) = hi4(v);
    }
    __syncthreads();
    const int j2 = tid & 15, bu = tid >> 4;
#pragma unroll 4
    for (int k = 0; k < 128; ++k) {
        int unit = bu + k * 16;        // 0..2047 -> (c, i2)
        int c = unit & 127, i2 = unit >> 7;
        float a = ab[c], bb = ab[128 + c];
        float v = fmaxf(a * (float)L[(i2 * 16 + j2) * 132 + c] + bb, 0.f);
        out[(((size_t)b * 128 + c) * 256 + i1 * 16 + i2) * 256 + j1 * 16 + j2] = v;
    }
}

// =====================================================================================
extern "C" void kernel_launch(void* const* d_in, const int* in_sizes, int n_in, void* d_out,
                              int out_size, void* d_ws, size_t ws_size, hipStream_t stream) {
    (void)in_sizes; (void)n_in; (void)out_size; (void)ws_size;
    const float* x = (const float*)d_in[0];
    const float* w1x = (const float*)d_in[1];
    const float* b1x = (const float*)d_in[2];
    const float* w1y = (const float*)d_in[3];
    const float* b1y = (const float*)d_in[4];
    const float* w1o = (const float*)d_in[5];
    const float* b1o = (const float*)d_in[6];
    const float* g1 = (const float*)d_in[7];
    const float* be1 = (const float*)d_in[8];
    const float* w2x = (const float*)d_in[9];
    const float* b2x = (const float*)d_in[10];
    const float* w2y = (const float*)d_in[11];
    const float* b2y = (const float*)d_in[12];
    const float* w2o = (const float*)d_in[13];
    const float* b2o = (const float*)d_in[14];
    const float* g2 = (const float*)d_in[15];
    const float* be2 = (const float*)d_in[16];

    // d_out doubles as scratch: [0,64MiB) Xall f16, [64MiB,128MiB) U1 f16 (both dead
    // before final_kernel rewrites d_out as fp32).
    f16* Xall = (f16*)d_out;
    f16* U1 = (f16*)((char*)d_out + 67108864);
    f16* U2 = (f16*)d_ws;
    f16* Wbf = (f16*)((char*)d_ws + 67108864);                  // fused [2][256][128] f16
    float* gstats = (float*)((char*)d_ws + 67108864 + 131072);  // [2][256]
    float* bnab = gstats + 512;                                 // [2][256]

    (void)hipMemsetAsync(gstats, 0, 2048, stream);
    wconv_kernel<<<256, 256, 0, stream>>>(w1x, w1y, w1o, w2x, w2y, w2o, Wbf);
    repack_kernel<<<1024, 512, 0, stream>>>(x, Xall);

    att_kernel<1><<<1024, 512, 0, stream>>>(Xall, Wbf, b1x, b1y, b1o, (const float*)nullptr, U1,
                                            gstats, 32768, 128);
    bnfix_kernel<<<1, 128, 0, stream>>>(gstats, g1, be1, bnab);
    att_kernel<2><<<1024, 512, 0, stream>>>(U1, Wbf + 32768, b2x, b2y, b2o, bnab, U2,
                                            gstats + 256, 128, 32768);
    bnfix_kernel<<<1, 128, 0, stream>>>(gstats + 256, g2, be2, bnab + 256);
    final_kernel<<<1024, 256, 0, stream>>>(U2, bnab + 256, (float*)d_out);
}

// Round 7
// 269.381 us; speedup vs baseline: 1.4986x; 1.1119x over previous
//
#include <hip/hip_runtime.h>

typedef _Float16 f16;
typedef f16 f16x2 __attribute__((ext_vector_type(2)));
typedef f16 f16x4 __attribute__((ext_vector_type(4)));
typedef f16 f16x8 __attribute__((ext_vector_type(8)));
typedef float f32x4 __attribute__((ext_vector_type(4)));
typedef float f32x16 __attribute__((ext_vector_type(16)));
typedef unsigned int u32;
typedef u32 u32x2 __attribute__((ext_vector_type(2)));
typedef u32 u32x4 __attribute__((ext_vector_type(4)));

#define MFMA32(a, b, c) __builtin_amdgcn_mfma_f32_32x32x16_f16((a), (b), (c), 0, 0, 0)

__device__ __forceinline__ u32 pk2(float a, float b) {
    return __builtin_bit_cast(u32, __builtin_amdgcn_cvt_pkrtz(a, b));
}
__device__ __forceinline__ f16x4 pk4(float a, float b, float c, float d) {
    u32x2 t = {pk2(a, b), pk2(c, d)};
    return __builtin_bit_cast(f16x4, t);
}
__device__ __forceinline__ f16x4 lo4(f16x8 v) { return __builtin_shufflevector(v, v, 0, 1, 2, 3); }
__device__ __forceinline__ f16x4 hi4(f16x8 v) { return __builtin_shufflevector(v, v, 4, 5, 6, 7); }

// ---------------- LDS layout (bytes) ----------------
// [0,65536):       phase1 W fragment-linear [8 tiles][8 ks][64 lanes][16B]
//                  (Wo tiles 0-3, Wq 4-5, Wk 6-7); phase2 Vf [16 ts][4 ct][64][16B]
// [65536,98304):   Yf psi^T fragments [8 kt][4 ks][64][16B]
// [98304,131072):  per-wave 4KB scratch: Tf [4 ks][64][16B], then epi [16][256B]
// [131072,132096): SST f32[256] BN partials
#define OFF_Y   65536
#define OFF_SC  98304
#define OFF_SST 131072
#define LDS_ATT 132096

// =====================================================================================
// repack: x fp32 [B,C,H,W] -> Xall f16 [b][n2=(i2,j2)][n1=(i1,j1)][c]
// =====================================================================================
__global__ __launch_bounds__(512) void repack_kernel(const float* __restrict__ x,
                                                     f16* __restrict__ Xall) {
    __shared__ f16 XT[128 * 264];     // [c][w], padded
    const int tid = threadIdx.x, g = blockIdx.x;
    const int b = g >> 8, i1 = (g >> 4) & 15, i2 = g & 15;
    const int h = i1 * 16 + i2;
    {
        const int c = tid >> 2, wq = (tid & 3) * 64;
        const float* src = x + (((size_t)b * 128 + c) * 256 + h) * 256 + wq;
        f16* dst = XT + c * 264 + wq;
#pragma unroll
        for (int i = 0; i < 16; ++i) {
            f32x4 v = *(const f32x4*)(src + i * 4);
            f16x4 o = {(f16)v[0], (f16)v[1], (f16)v[2], (f16)v[3]};
            *(f16x4*)(dst + i * 4) = o;
        }
    }
    __syncthreads();
    {
        const int w = tid >> 1, ch = (tid & 1) * 64;   // w = j1*16 + j2
        const int j1 = w >> 4, j2 = w & 15;
        f16* dst = Xall + (((size_t)b * 256 + i2 * 16 + j2) * 256 + i1 * 16 + j1) * 128 + ch;
#pragma unroll
        for (int i = 0; i < 8; ++i) {
            f16x8 v;
#pragma unroll
            for (int j = 0; j < 8; ++j) v[j] = XT[(ch + i * 8 + j) * 264 + w];
            *(f16x8*)(dst + i * 8) = v;
        }
    }
}

// =====================================================================================
// weight conversion fp32 -> f16 into FRAGMENT-LINEAR layout, 32768 f16 per pass:
// Wf[pass][tile r][ks][lane][j]: element = Wrow[r*32+(lane&31)][ks*16+(lane>>5)*8+j]
// tiles: 0-3 = Wo rows 0-127, 4-5 = Wq rows 128-191, 6-7 = Wk rows 192-255
// =====================================================================================
__global__ void wconv_kernel(const float* __restrict__ w1x, const float* __restrict__ w1y,
                             const float* __restrict__ w1o, const float* __restrict__ w2x,
                             const float* __restrict__ w2y, const float* __restrict__ w2o,
                             f16* __restrict__ Wf) {
    int i = blockIdx.x * 256 + threadIdx.x;      // 65536 total
    int p = i >> 15, idx = i & 32767;
    int j = idx & 7, lane = (idx >> 3) & 63, ks = (idx >> 9) & 7, r = idx >> 12;  // r in 0..7
    int row = r * 32 + (lane & 31);
    int c = ks * 16 + (lane >> 5) * 8 + j;
    const float* s;
    if (p == 0) s = (row < 128) ? w1o + row * 128 : (row < 192) ? w1x + (row - 128) * 128
                                                               : w1y + (row - 192) * 128;
    else        s = (row < 128) ? w2o + row * 128 : (row < 192) ? w2x + (row - 128) * 128
                                                               : w2y + (row - 192) * 128;
    Wf[i] = (f16)s[c];
}

// =====================================================================================
// fused per-block attention, all 32x32x16 MFMA:
//   out = softmax(theta psi) @ (X Wo^T + bo)
// Each wave owns 32 tokens. Fragment-linear LDS for W/psi/T/V'' -> conflict-free
// ds_read_b128. P built in-register from S^T C-frags via cvt_pkrtz + permlane32_swap.
// =====================================================================================
template <int PASS>
__global__ __launch_bounds__(512, 2) void att_kernel(
    const f16* __restrict__ Xin, const f16* __restrict__ Wf, const float* __restrict__ bq,
    const float* __restrict__ bk, const float* __restrict__ bo, const float* __restrict__ bnab,
    f16* __restrict__ Uout, float* __restrict__ gstats, int t_stride, int s_stride) {
    __shared__ __align__(16) char smem[LDS_ATT];
    float* SST = (float*)(smem + OFF_SST);
    const int tid = threadIdx.x;
    const int w = tid >> 6, l = tid & 63, hl = l >> 5, l31 = l & 31;
    const int g = blockIdx.x, R0 = w * 32;
    char* scb = smem + OFF_SC + w * 4096;

    if (tid < 256) SST[tid] = 0.f;

    // ---- W preload: straight 64KB linear copy (already fragment-ordered) ----
#pragma unroll
    for (int j = 0; j < 8; ++j) {
        int byte = (j * 512 + tid) * 16;
        *(f16x8*)(smem + byte) = *(const f16x8*)((const char*)Wf + byte);
    }

    // ---- X A-frags: t = R0+l31, slice ks: c = ks*16 + hl*8 + j ----
    const f16* src = Xin + (size_t)g * 32768 + (R0 + l31) * 128 + hl * 8;
    f16x8 afr[8];
#pragma unroll
    for (int ks = 0; ks < 8; ++ks) afr[ks] = *(const f16x8*)(src + ks * 16);
    if constexpr (PASS == 2) {   // BN1 + ReLU on the fly
#pragma unroll
        for (int ks = 0; ks < 8; ++ks) {
            const int c0 = ks * 16 + hl * 8;
            f32x4 a0 = *(const f32x4*)(bnab + c0), a1 = *(const f32x4*)(bnab + c0 + 4);
            f32x4 s0 = *(const f32x4*)(bnab + 128 + c0), s1 = *(const f32x4*)(bnab + 132 + c0);
            f16x8 v = afr[ks];
#pragma unroll
            for (int j = 0; j < 4; ++j) {
                v[j]     = (f16)fmaxf(a0[j] * (float)v[j]     + s0[j], 0.f);
                v[j + 4] = (f16)fmaxf(a1[j] * (float)v[j + 4] + s1[j], 0.f);
            }
            afr[ks] = v;
        }
    }
    __syncthreads();   // #0: W resident

    // ---- GEMM1: theta (Wq tiles 4-5), psi (Wk tiles 6-7) ----
    f32x16 aT[2] = {}, aP[2] = {};
#pragma unroll
    for (int ks = 0; ks < 8; ++ks)
#pragma unroll
        for (int nt = 0; nt < 2; ++nt) {
            f16x8 Bq = *(const f16x8*)(smem + (((4 + nt) * 8 + ks) * 64 + l) * 16);
            f16x8 Bk = *(const f16x8*)(smem + (((6 + nt) * 8 + ks) * 64 + l) * 16);
            aT[nt] = MFMA32(afr[ks], Bq, aT[nt]);
            aP[nt] = MFMA32(afr[ks], Bk, aP[nt]);
        }
    // scatter theta->Tf (per-wave, B-frag order), psi->Yf (shared, A-frag order)
    {
        const int lf = (l31 >> 3) & 1;       // m bit 3 -> lane-field hi
        const int msub = l31 >> 4;           // m bit 4 -> frag index low bit
        const int jb = (l31 & 7) * 2;
#pragma unroll
        for (int nt = 0; nt < 2; ++nt) {
            float bqv = bq[nt * 32 + l31], bkv = bk[nt * 32 + l31];
            char* bT = scb + (((nt * 2 + msub) * 64) + 32 * lf) * 16 + jb;
            char* bY = smem + OFF_Y + (((w * 4 + nt * 2 + msub) * 64) + 32 * lf) * 16 + jb;
#pragma unroll
            for (int r = 0; r < 16; ++r) {
                int tl = (r & 3) + 8 * (r >> 2) + 4 * hl;
                *(f16*)(bT + tl * 16) = (f16)(aT[nt][r] + bqv);
                *(f16*)(bY + tl * 16) = (f16)(aP[nt][r] + bkv);
            }
        }
    }
    // hoist T B-frags (own-wave data; frees scratch for epilogue)
    f16x8 tb[4];
#pragma unroll
    for (int ks = 0; ks < 4; ++ks) tb[ks] = *(const f16x8*)(scb + (ks * 64 + l) * 16);

    // ---- V'' GEMM (Wo tiles 0-3) ----
    f32x16 aV[4] = {};
#pragma unroll
    for (int ks = 0; ks < 8; ++ks)
#pragma unroll
        for (int ct = 0; ct < 4; ++ct) {
            f16x8 Bo = *(const f16x8*)(smem + ((ct * 8 + ks) * 64 + l) * 16);
            aV[ct] = MFMA32(afr[ks], Bo, aV[ct]);
        }
    __syncthreads();   // #1: all W reads done -> region becomes Vf

    // ---- V''+bo -> Vf (B-frag order), packed b64 (4 consecutive tokens/reg-quad) ----
#pragma unroll
    for (int ct = 0; ct < 4; ++ct) {
        float bov = bo[ct * 32 + l31];
#pragma unroll
        for (int q = 0; q < 4; ++q) {
            int ts = 2 * w + (q >> 1);
            f16x4 pv = pk4(aV[ct][4 * q + 0] + bov, aV[ct][4 * q + 1] + bov,
                           aV[ct][4 * q + 2] + bov, aV[ct][4 * q + 3] + bov);
            *(f16x4*)(smem + (((ts * 4 + ct) * 64) + l31 + 32 * (q & 1)) * 16 + 8 * hl) = pv;
        }
    }
    __syncthreads();   // #2: Vf + Yf complete

    // ---- S^T: col t = R0+l31 on lanes, all 256 k in regs ----
    f32x16 s[8] = {};
    __builtin_amdgcn_s_setprio(1);
#pragma unroll
    for (int kt = 0; kt < 8; ++kt)
#pragma unroll
        for (int ks = 0; ks < 4; ++ks) {
            f16x8 ay = *(const f16x8*)(smem + OFF_Y + (((kt * 4 + ks) * 64) + l) * 16);
            s[kt] = MFMA32(ay, tb[ks], s[kt]);
        }
    __builtin_amdgcn_s_setprio(0);

    // ---- softmax over k: per-lane 128 values + hl-partner combine ----
    float mx = -1e30f;
#pragma unroll
    for (int kt = 0; kt < 8; ++kt) {
        float m0 = fmaxf(fmaxf(s[kt][0], s[kt][1]), fmaxf(s[kt][2], s[kt][3]));
        float m1 = fmaxf(fmaxf(s[kt][4], s[kt][5]), fmaxf(s[kt][6], s[kt][7]));
        float m2 = fmaxf(fmaxf(s[kt][8], s[kt][9]), fmaxf(s[kt][10], s[kt][11]));
        float m3 = fmaxf(fmaxf(s[kt][12], s[kt][13]), fmaxf(s[kt][14], s[kt][15]));
        mx = fmaxf(mx, fmaxf(fmaxf(m0, m1), fmaxf(m2, m3)));
    }
    mx = fmaxf(mx, __shfl_xor(mx, 32));
    float sum = 0.f;
#pragma unroll
    for (int kt = 0; kt < 8; ++kt)
#pragma unroll
        for (int e = 0; e < 16; ++e) {
            float p = __expf(s[kt][e] - mx);
            s[kt][e] = p;
            sum += p;
        }
    sum += __shfl_xor(sum, 32);
    const float rs = 1.f / sum;

    // ---- PV: A-frags built in-register (cvt_pkrtz + permlane32_swap), B from Vf ----
    f32x16 o[4] = {};
#pragma unroll
    for (int kt = 0; kt < 8; ++kt) {
#pragma unroll
        for (int ks = 0; ks < 2; ++ks) {
            u32 a0 = pk2(s[kt][8 * ks + 0] * rs, s[kt][8 * ks + 1] * rs);
            u32 a1 = pk2(s[kt][8 * ks + 2] * rs, s[kt][8 * ks + 3] * rs);
            u32 b0 = pk2(s[kt][8 * ks + 4] * rs, s[kt][8 * ks + 5] * rs);
            u32 b1 = pk2(s[kt][8 * ks + 6] * rs, s[kt][8 * ks + 7] * rs);
            u32x2 r0 = __builtin_amdgcn_permlane32_swap(a0, b0, false, false);
            u32x2 r1 = __builtin_amdgcn_permlane32_swap(a1, b1, false, false);
            u32x4 aw = {r0.x, r1.x, r0.y, r1.y};
            f16x8 ap = __builtin_bit_cast(f16x8, aw);
            __builtin_amdgcn_s_setprio(1);
#pragma unroll
            for (int ct = 0; ct < 4; ++ct) {
                f16x8 bv = *(const f16x8*)(smem + ((((kt * 2 + ks) * 4 + ct) * 64) + l) * 16);
                o[ct] = MFMA32(ap, bv, o[ct]);
            }
            __builtin_amdgcn_s_setprio(0);
        }
    }

    // ---- BN stat partials: each lane owns one c per ct ----
#pragma unroll
    for (int ct = 0; ct < 4; ++ct) {
        float ss = 0.f, sq = 0.f;
#pragma unroll
        for (int e = 0; e < 16; ++e) {
            float v = o[ct][e];
            ss += v;
            sq += v * v;
        }
        ss += __shfl_xor(ss, 32);
        sq += __shfl_xor(sq, 32);
        if (hl == 0) {
            atomicAdd(&SST[ct * 32 + l31], ss);
            atomicAdd(&SST[128 + ct * 32 + l31], sq);
        }
    }

    // ---- store: two 16-row rounds via per-wave LDS transpose ----
    const size_t ub = (size_t)(g >> 8) * 8388608 + (size_t)(g & 255) * (size_t)s_stride;
#pragma unroll
    for (int ro = 0; ro < 2; ++ro) {
#pragma unroll
        for (int ct = 0; ct < 4; ++ct)
#pragma unroll
            for (int rr = 0; rr < 8; ++rr) {
                int r = ro * 8 + rr;
                int tl2 = (r & 3) + 8 * ((r >> 2) & 1) + 4 * hl;
                int c = ct * 32 + l31;
                *(f16*)(scb + ((tl2 * 256 + c * 2) ^ (((tl2 >> 2) & 3) << 4))) = (f16)o[ct][r];
            }
#pragma unroll
        for (int i = 0; i < 4; ++i) {
            int row = i * 4 + (l >> 4);
            f16x8 v8 = *(const f16x8*)(scb + ((row * 256 + (l & 15) * 16) ^
                                              (((row >> 2) & 3) << 4)));
            int t = R0 + ro * 16 + row;
            *(f16x8*)(Uout + ub + (size_t)t * (size_t)t_stride + (l & 15) * 8) = v8;
        }
    }
    __syncthreads();   // #3
    if (tid < 256) atomicAdd(&gstats[tid], SST[tid]);
}

// =====================================================================================
// BN stats finalize: (sum, sumsq) -> (a, b) with y = a*x + b
// =====================================================================================
__global__ void bnfix_kernel(const float* __restrict__ gstats, const float* __restrict__ gamma,
                             const float* __restrict__ beta, float* __restrict__ ab) {
    int c = threadIdx.x;
    if (c < 128) {
        const float inv = 1.f / 262144.f;
        float mean = gstats[c] * inv;
        float var = gstats[128 + c] * inv - mean * mean;
        float rstd = rsqrtf(var + 1e-5f);
        float a = gamma[c] * rstd;
        ab[c] = a;
        ab[128 + c] = beta[c] - mean * a;
    }
}

// =====================================================================================
// final: U2 f16 [b][n1][n2][c] -> BN2+ReLU -> out fp32 [B,C,H,W]
// =====================================================================================
__global__ __launch_bounds__(256) void final_kernel(const f16* __restrict__ U2,
                                                    const float* __restrict__ ab,
                                                    float* __restrict__ out) {
    __shared__ f16 L[256 * 132];      // [n2][c] padded
    const int tid = threadIdx.x, g = blockIdx.x;
    const int b = g >> 8, i1 = (g >> 4) & 15, j1 = g & 15;
    const f16* src = U2 + (size_t)g * 32768;
#pragma unroll
    for (int e = 0; e < 16; ++e) {
        int u = e * 2048 + tid * 8;
        int row = u >> 7, c0 = u & 127;
        f16x8 v = *(const f16x8*)(src + u);
        f16* dst = L + row * 132 + c0;
        *(f16x4*)dst = lo4(v);
        *(f16x4*)(dst + 4) = hi4(v);
    }
    __syncthreads();
    const int j2 = tid & 15, bu = tid >> 4;
#pragma unroll 4
    for (int k = 0; k < 128; ++k) {
        int unit = bu + k * 16;        // 0..2047 -> (c, i2)
        int c = unit & 127, i2 = unit >> 7;
        float a = ab[c], bb = ab[128 + c];
        float v = fmaxf(a * (float)L[(i2 * 16 + j2) * 132 + c] + bb, 0.f);
        out[(((size_t)b * 128 + c) * 256 + i1 * 16 + i2) * 256 + j1 * 16 + j2] = v;
    }
}

// =====================================================================================
extern "C" void kernel_launch(void* const* d_in, const int* in_sizes, int n_in, void* d_out,
                              int out_size, void* d_ws, size_t ws_size, hipStream_t stream) {
    (void)in_sizes; (void)n_in; (void)out_size; (void)ws_size;
    const float* x = (const float*)d_in[0];
    const float* w1x = (const float*)d_in[1];
    const float* b1x = (const float*)d_in[2];
    const float* w1y = (const float*)d_in[3];
    const float* b1y = (const float*)d_in[4];
    const float* w1o = (const float*)d_in[5];
    const float* b1o = (const float*)d_in[6];
    const float* g1 = (const float*)d_in[7];
    const float* be1 = (const float*)d_in[8];
    const float* w2x = (const float*)d_in[9];
    const float* b2x = (const float*)d_in[10];
    const float* w2y = (const float*)d_in[11];
    const float* b2y = (const float*)d_in[12];
    const float* w2o = (const float*)d_in[13];
    const float* b2o = (const float*)d_in[14];
    const float* g2 = (const float*)d_in[15];
    const float* be2 = (const float*)d_in[16];

    // d_out doubles as scratch: [0,64MiB) Xall f16, [64MiB,128MiB) U1 f16 (both dead
    // before final_kernel rewrites d_out as fp32).
    f16* Xall = (f16*)d_out;
    f16* U1 = (f16*)((char*)d_out + 67108864);
    f16* U2 = (f16*)d_ws;
    f16* Wbf = (f16*)((char*)d_ws + 67108864);                  // fragment-linear [2][32768]
    float* gstats = (float*)((char*)d_ws + 67108864 + 262144);  // [2][256]
    float* bnab = gstats + 512;                                 // [2][256]

    (void)hipMemsetAsync(gstats, 0, 2048, stream);
    wconv_kernel<<<256, 256, 0, stream>>>(w1x, w1y, w1o, w2x, w2y, w2o, Wbf);
    repack_kernel<<<1024, 512, 0, stream>>>(x, Xall);

    att_kernel<1><<<1024, 512, 0, stream>>>(Xall, Wbf, b1x, b1y, b1o, (const float*)nullptr, U1,
                                            gstats, 32768, 128);
    bnfix_kernel<<<1, 128, 0, stream>>>(gstats, g1, be1, bnab);
    att_kernel<2><<<1024, 512, 0, stream>>>(U1, Wbf + 32768, b2x, b2y, b2o, bnab, U2,
                                            gstats + 256, 128, 32768);
    bnfix_kernel<<<1, 128, 0, stream>>>(gstats + 256, g2, be2, bnab + 256);
    final_kernel<<<1024, 256, 0, stream>>>(U2, bnab + 256, (float*)d_out);
}